// Round 2
// baseline (9557.724 us; speedup 1.0000x reference)
//
#include <hip/hip_runtime.h>
#include <stdint.h>

// FPS: B=4, N=16*8192=131072 points, C=64, K=128 samples.
// One persistent cooperative kernel; 256 blocks/batch; parity-double-buffered
// tagged slot barrier per round. Distance kept in registers (each point owned
// by one thread). Distance sum matches numpy's pairwise 8-accumulator order
// bit-exactly (no FMA, mod-8 stripes, ((r0+r1)+(r2+r3))+((r4+r5)+(r6+r7))).

#define NB 4
#define NPTS 131072
#define NC 64
#define NK 128
#define BPB 256              // blocks per batch
#define NT 256               // threads per block
#define STRIDE (BPB * NT)    // 65536 threads per batch; 2 points per thread

__device__ __forceinline__ void amax2(float& bd, int& bi, float od, int oi) {
  // max by distance; tie -> smaller index (np.argmax first-occurrence)
  if (od > bd || (od == bd && oi < bi)) { bd = od; bi = oi; }
}

// numpy-exact sum((p-c)**2) over 64 contiguous f32:
// pairwise_sum 8-accumulator path, stripe j accumulates elems e with e%8==j.
__device__ __forceinline__ float dist_np(const float4* __restrict__ p4,
                                         const float4* __restrict__ c4) {
#pragma clang fp contract(off)
  float r0, r1, r2, r3, r4, r5, r6, r7;
  {
    float4 a = p4[0], b = c4[0];
    float dx = a.x - b.x, dy = a.y - b.y, dz = a.z - b.z, dw = a.w - b.w;
    r0 = dx * dx; r1 = dy * dy; r2 = dz * dz; r3 = dw * dw;
    a = p4[1]; b = c4[1];
    dx = a.x - b.x; dy = a.y - b.y; dz = a.z - b.z; dw = a.w - b.w;
    r4 = dx * dx; r5 = dy * dy; r6 = dz * dz; r7 = dw * dw;
  }
#pragma unroll
  for (int blk = 1; blk < 8; ++blk) {
    float4 a = p4[2 * blk], b = c4[2 * blk];
    float dx = a.x - b.x, dy = a.y - b.y, dz = a.z - b.z, dw = a.w - b.w;
    r0 += dx * dx; r1 += dy * dy; r2 += dz * dz; r3 += dw * dw;
    a = p4[2 * blk + 1]; b = c4[2 * blk + 1];
    dx = a.x - b.x; dy = a.y - b.y; dz = a.z - b.z; dw = a.w - b.w;
    r4 += dx * dx; r5 += dy * dy; r6 += dz * dz; r7 += dw * dw;
  }
  return ((r0 + r1) + (r2 + r3)) + ((r4 + r5) + (r6 + r7));
}

__global__ __launch_bounds__(NT, 4) void fps_kernel(
    const float* __restrict__ points,          // (B, N, C)
    const int* __restrict__ finit,             // (B,)
    float* __restrict__ out,                   // B*K*C sampled + B*K centroids
    unsigned long long* __restrict__ slots) {  // ws: [2][B][BPB] tagged packs
  const int b   = blockIdx.x >> 8;
  const int blk = blockIdx.x & (BPB - 1);
  const int tid = threadIdx.x;

  __shared__ float cent[NC];
  __shared__ float red_d[NT / 64];
  __shared__ int   red_i[NT / 64];
  __shared__ int   f_sh;
  __shared__ int   hist[NK];

  const float* __restrict__ P = points + (size_t)b * NPTS * NC;

  int f = finit[b];
  if (tid == 0) hist[0] = f;

  const int i0 = blk * NT + tid;        // point 0
  const int i1 = i0 + STRIDE;           // point 1 (i0 < i1 always)
  float dloc0 = 1e10f, dloc1 = 1e10f;   // reference INF init

  for (int k = 0; k < NK - 1; ++k) {
    // ---- stage centroid row into LDS
    if (tid < NC / 4) {
      ((float4*)cent)[tid] = ((const float4*)(P + (size_t)f * NC))[tid];
    }
    __syncthreads();

    // ---- distance update + thread-local argmax (first-occurrence ties)
    float bd = -1.0f; int bi = 0;
    {
      const float d = dist_np((const float4*)(P + (size_t)i0 * NC),
                              (const float4*)cent);
      dloc0 = fminf(dloc0, d);          // exact; 1e10 >> any real distance
      if (dloc0 > bd) { bd = dloc0; bi = i0; }
    }
    {
      const float d = dist_np((const float4*)(P + (size_t)i1 * NC),
                              (const float4*)cent);
      dloc1 = fminf(dloc1, d);
      if (dloc1 > bd) { bd = dloc1; bi = i1; }  // strict >: keeps smaller idx
    }

    // ---- wave reduce, then cross-wave via LDS
    #pragma unroll
    for (int off = 32; off > 0; off >>= 1) {
      const float od = __shfl_down(bd, off);
      const int   oi = __shfl_down(bi, off);
      amax2(bd, bi, od, oi);
    }
    if ((tid & 63) == 0) { red_d[tid >> 6] = bd; red_i[tid >> 6] = bi; }
    __syncthreads();

    // ---- thread 0 publishes block best into parity slot, tag = k+1
    const int par = k & 1;
    unsigned long long* S = slots + (size_t)par * NB * BPB + (size_t)b * BPB;
    if (tid == 0) {
      #pragma unroll
      for (int w = 1; w < NT / 64; ++w) amax2(bd, bi, red_d[w], red_i[w]);
      // pack: [63:32]=dist bits, [31:24]=tag (k+1), [23:0]=idx (N < 2^24)
      // ws poison 0xAA gives tag 170, never equal to k+1 in [1,127].
      const unsigned long long pack =
          ((unsigned long long)__float_as_uint(bd) << 32) |
          ((unsigned long long)(unsigned)((k + 1) & 0xff) << 24) |
          (unsigned long long)(unsigned)bi;
      __hip_atomic_store(&S[blk], pack, __ATOMIC_RELEASE,
                         __HIP_MEMORY_SCOPE_AGENT);
    }

    // ---- wave 0 polls all 256 per-batch slots; parity buffer is ABA-free:
    // slot [par] for round k is only overwritten at round k+2, which is gated
    // on every block having completed round k's poll.
    if (tid < 64) {
      float pd = -1.0f; int pi = 0;
      for (int s = tid; s < BPB; s += 64) {
        unsigned long long v;
        for (;;) {
          v = __hip_atomic_load(&S[s], __ATOMIC_ACQUIRE,
                                __HIP_MEMORY_SCOPE_AGENT);
          if (((unsigned)(v >> 24) & 0xffu) == (unsigned)((k + 1) & 0xff))
            break;
          __builtin_amdgcn_s_sleep(1);
        }
        amax2(pd, pi, __uint_as_float((unsigned)(v >> 32)),
              (int)(v & 0xffffffu));
      }
      #pragma unroll
      for (int off = 32; off > 0; off >>= 1) {
        const float od = __shfl_down(pd, off);
        const int   oi = __shfl_down(pi, off);
        amax2(pd, pi, od, oi);
      }
      if (tid == 0) { f_sh = pi; hist[k + 1] = pi; }
    }
    __syncthreads();
    f = f_sh;
  }

  // ---- epilogue: block 0 of each batch writes centroids then sampled rows
  if (blk == 0) {
    for (int e = tid; e < NK; e += NT) {
      out[NB * NK * NC + b * NK + e] = (float)hist[e];  // exact: idx < 2^24
    }
    for (int e = tid; e < NK * NC; e += NT) {
      const int kk = e >> 6, c = e & (NC - 1);
      out[((size_t)b * NK + kk) * NC + c] = P[(size_t)hist[kk] * NC + c];
    }
  }
}

extern "C" void kernel_launch(void* const* d_in, const int* in_sizes, int n_in,
                              void* d_out, int out_size, void* d_ws,
                              size_t ws_size, hipStream_t stream) {
  const float* points = (const float*)d_in[0];
  const int* finit = (const int*)d_in[1];
  float* out = (float*)d_out;
  unsigned long long* slots = (unsigned long long*)d_ws;  // 2*4*256*8B = 16 KB

  void* args[] = {&points, &finit, &out, &slots};
  hipError_t err = hipLaunchCooperativeKernel(
      (void*)fps_kernel, dim3(NB * BPB), dim3(NT), args, 0, stream);
  if (err != hipSuccess) {
    // fallback: plain launch (1024 blocks of 4 waves co-schedule on 256 CUs)
    fps_kernel<<<dim3(NB * BPB), dim3(NT), 0, stream>>>(points, finit, out,
                                                        slots);
  }
}

// Round 6
// 2406.724 us; speedup vs baseline: 3.9713x; 3.9713x over previous
//
#include <hip/hip_runtime.h>
#include <stdint.h>

// FPS: B=4, N=16*8192=131072 points, C=64, K=128 samples.
// Persistent cooperative kernel; 256 blocks/batch; per-round hierarchical
// barrier using RELAXED agent-scope atomics only (tag+payload share one u64,
// so no acquire/release fences are needed -> no L2 writeback/invalidate
// storms, which dominated R2's 9.5 ms).
// Distance sum matches numpy's pairwise 8-accumulator order bit-exactly.

#define NB 4
#define NPTS 131072
#define NC 64
#define NK 128
#define BPB 256              // blocks per batch
#define NT 256               // threads per block
#define STRIDE (BPB * NT)    // 65536 threads per batch; 2 points per thread

__device__ __forceinline__ void amax2(float& bd, int& bi, float od, int oi) {
  // max by distance; tie -> smaller index (np.argmax first-occurrence)
  if (od > bd || (od == bd && oi < bi)) { bd = od; bi = oi; }
}

// numpy-exact sum((p-c)**2) over 64 contiguous f32:
// pairwise_sum 8-accumulator path, stripe j accumulates elems e with e%8==j.
__device__ __forceinline__ float dist_np(const float4* __restrict__ p4,
                                         const float4* __restrict__ c4) {
#pragma clang fp contract(off)
  float r0, r1, r2, r3, r4, r5, r6, r7;
  {
    float4 a = p4[0], b = c4[0];
    float dx = a.x - b.x, dy = a.y - b.y, dz = a.z - b.z, dw = a.w - b.w;
    r0 = dx * dx; r1 = dy * dy; r2 = dz * dz; r3 = dw * dw;
    a = p4[1]; b = c4[1];
    dx = a.x - b.x; dy = a.y - b.y; dz = a.z - b.z; dw = a.w - b.w;
    r4 = dx * dx; r5 = dy * dy; r6 = dz * dz; r7 = dw * dw;
  }
#pragma unroll
  for (int blk = 1; blk < 8; ++blk) {
    float4 a = p4[2 * blk], b = c4[2 * blk];
    float dx = a.x - b.x, dy = a.y - b.y, dz = a.z - b.z, dw = a.w - b.w;
    r0 += dx * dx; r1 += dy * dy; r2 += dz * dz; r3 += dw * dw;
    a = p4[2 * blk + 1]; b = c4[2 * blk + 1];
    dx = a.x - b.x; dy = a.y - b.y; dz = a.z - b.z; dw = a.w - b.w;
    r4 += dx * dx; r5 += dy * dy; r6 += dz * dz; r7 += dw * dw;
  }
  return ((r0 + r1) + (r2 + r3)) + ((r4 + r5) + (r6 + r7));
}

__global__ __launch_bounds__(NT, 4) void fps_kernel(
    const float* __restrict__ points,         // (B, N, C)
    const int* __restrict__ finit,            // (B,)
    float* __restrict__ out,                  // B*K*C sampled + B*K centroids
    unsigned long long* __restrict__ slots,   // ws: [B][BPB] tagged packs
    unsigned long long* __restrict__ fbc) {   // ws: [B] tagged f broadcast
  const int b   = blockIdx.x >> 8;
  const int blk = blockIdx.x & (BPB - 1);
  const int tid = threadIdx.x;

  __shared__ float cent[NC];
  __shared__ float red_d[NT / 64];
  __shared__ int   red_i[NT / 64];
  __shared__ int   f_sh;
  __shared__ int   hist[NK];

  const float* __restrict__ P = points + (size_t)b * NPTS * NC;
  unsigned long long* S = slots + b * BPB;

  int f = finit[b];
  if (blk == 0 && tid == 0) hist[0] = f;

  const int i0 = blk * NT + tid;        // point 0
  const int i1 = i0 + STRIDE;           // point 1 (i0 < i1 always)
  float dloc0 = 1e10f, dloc1 = 1e10f;   // reference INF init

  for (int k = 0; k < NK - 1; ++k) {
    // ---- stage centroid row into LDS
    if (tid < NC / 4) {
      ((float4*)cent)[tid] = ((const float4*)(P + (size_t)f * NC))[tid];
    }
    __syncthreads();

    // ---- distance update + thread-local argmax (first-occurrence ties)
    float bd = -1.0f; int bi = 0;
    {
      const float d = dist_np((const float4*)(P + (size_t)i0 * NC),
                              (const float4*)cent);
      dloc0 = fminf(dloc0, d);          // exact; 1e10 >> any real distance
      if (dloc0 > bd) { bd = dloc0; bi = i0; }
    }
    {
      const float d = dist_np((const float4*)(P + (size_t)i1 * NC),
                              (const float4*)cent);
      dloc1 = fminf(dloc1, d);
      if (dloc1 > bd) { bd = dloc1; bi = i1; }  // strict >: keeps smaller idx
    }

    // ---- wave reduce, then cross-wave via LDS
    #pragma unroll
    for (int off = 32; off > 0; off >>= 1) {
      const float od = __shfl_down(bd, off);
      const int   oi = __shfl_down(bi, off);
      amax2(bd, bi, od, oi);
    }
    if ((tid & 63) == 0) { red_d[tid >> 6] = bd; red_i[tid >> 6] = bi; }
    __syncthreads();

    const unsigned tag = (unsigned)(k + 1);  // unique per round, in [1,127]

    // ---- thread 0 publishes block best (tag+payload in ONE u64, relaxed)
    if (tid == 0) {
      #pragma unroll
      for (int w = 1; w < NT / 64; ++w) amax2(bd, bi, red_d[w], red_i[w]);
      // pack: [63:32]=dist bits, [31:24]=tag, [23:0]=idx (N < 2^24)
      // ws poison 0xAA decodes to tag 170, never equal to any real tag.
      const unsigned long long pack =
          ((unsigned long long)__float_as_uint(bd) << 32) |
          ((unsigned long long)(tag & 0xffu) << 24) |
          (unsigned long long)(unsigned)bi;
      __hip_atomic_store(&S[blk], pack, __ATOMIC_RELAXED,
                         __HIP_MEMORY_SCOPE_AGENT);
    }

    if (blk == 0) {
      // ---- leader: wave 0 gathers all 256 slots (contiguous -> coalesced),
      // reduces, broadcasts f via one tagged word.
      if (tid < 64) {
        float pd = -1.0f; int pi = 0;
        #pragma unroll
        for (int q = 0; q < BPB / 64; ++q) {
          const int s = tid + q * 64;
          unsigned long long v;
          for (;;) {
            v = __hip_atomic_load(&S[s], __ATOMIC_RELAXED,
                                  __HIP_MEMORY_SCOPE_AGENT);
            if (((unsigned)(v >> 24) & 0xffu) == tag) break;
            __builtin_amdgcn_s_sleep(1);
          }
          amax2(pd, pi, __uint_as_float((unsigned)(v >> 32)),
                (int)(v & 0xffffffu));
        }
        #pragma unroll
        for (int off = 32; off > 0; off >>= 1) {
          const float od = __shfl_down(pd, off);
          const int   oi = __shfl_down(pi, off);
          amax2(pd, pi, od, oi);
        }
        if (tid == 0) {
          f_sh = pi;
          hist[k + 1] = pi;
          const unsigned long long fp =
              ((unsigned long long)(tag & 0xffu) << 24) |
              (unsigned long long)(unsigned)pi;
          __hip_atomic_store(&fbc[b], fp, __ATOMIC_RELAXED,
                             __HIP_MEMORY_SCOPE_AGENT);
        }
      }
    } else {
      // ---- followers: one thread spins on ONE word
      if (tid == 0) {
        unsigned long long v;
        for (;;) {
          v = __hip_atomic_load(&fbc[b], __ATOMIC_RELAXED,
                                __HIP_MEMORY_SCOPE_AGENT);
          if (((unsigned)(v >> 24) & 0xffu) == tag) break;
          __builtin_amdgcn_s_sleep(1);
        }
        f_sh = (int)(v & 0xffffffu);
      }
    }
    __syncthreads();
    f = f_sh;
  }

  // ---- epilogue: leader block of each batch writes centroids + sampled rows
  if (blk == 0) {
    for (int e = tid; e < NK; e += NT) {
      out[NB * NK * NC + b * NK + e] = (float)hist[e];  // exact: idx < 2^24
    }
    for (int e = tid; e < NK * NC; e += NT) {
      const int kk = e >> 6, c = e & (NC - 1);
      out[((size_t)b * NK + kk) * NC + c] = P[(size_t)hist[kk] * NC + c];
    }
  }
}

extern "C" void kernel_launch(void* const* d_in, const int* in_sizes, int n_in,
                              void* d_out, int out_size, void* d_ws,
                              size_t ws_size, hipStream_t stream) {
  const float* points = (const float*)d_in[0];
  const int* finit = (const int*)d_in[1];
  float* out = (float*)d_out;
  unsigned long long* slots = (unsigned long long*)d_ws;  // 4*256*8 B = 8 KB
  unsigned long long* fbc =
      (unsigned long long*)((char*)d_ws + (size_t)NB * BPB * 8);  // 32 B

  void* args[] = {&points, &finit, &out, &slots, &fbc};
  hipError_t err = hipLaunchCooperativeKernel(
      (void*)fps_kernel, dim3(NB * BPB), dim3(NT), args, 0, stream);
  if (err != hipSuccess) {
    fps_kernel<<<dim3(NB * BPB), dim3(NT), 0, stream>>>(points, finit, out,
                                                        slots, fbc);
  }
}